// Round 3
// baseline (339.712 us; speedup 1.0000x reference)
//
#include <hip/hip_runtime.h>
#include <stdint.h>

#define NB 2
#define NS 2048
#define ND 1024
#define NH 16
#define NDK 64

typedef __attribute__((ext_vector_type(8))) short s8v;
typedef __attribute__((ext_vector_type(4))) float f4v;
typedef __attribute__((ext_vector_type(4))) unsigned short us4v;
typedef __attribute__((ext_vector_type(8))) unsigned short us8v;

__device__ __forceinline__ unsigned short f2bf(float f) {
  uint32_t u = __builtin_bit_cast(uint32_t, f);
  u = (u + 0x7fffu + ((u >> 16) & 1u)) >> 16;
  return (unsigned short)u;
}
__device__ __forceinline__ float bf2f(unsigned short h) {
  uint32_t u = ((uint32_t)h) << 16;
  return __builtin_bit_cast(float, u);
}

__device__ __forceinline__ void gload16(const void* g, void* l) {
  __builtin_amdgcn_global_load_lds(
      (const __attribute__((address_space(1))) void*)g,
      (__attribute__((address_space(3))) void*)l, 16, 0, 0);
}

// ---------------------------------------------------------------- convert x
__global__ void k_convert_x(const float* __restrict__ x, unsigned short* __restrict__ xbf) {
  int i = (blockIdx.x * 256 + threadIdx.x) * 4;
  float4 v = *(const float4*)(x + i);
  us4v o;
  o[0] = f2bf(v.x); o[1] = f2bf(v.y); o[2] = f2bf(v.z); o[3] = f2bf(v.w);
  *(us4v*)(xbf + i) = o;
}

// ------------------------------------------------- transpose+convert weights
// Wt[n][k] = W[k][n]; mat0..2 -> wt_qkv rows [mat*1024 + n], mat3 -> wt_o.
// mat0 (Wq) scaled by 1/8 (folds 1/sqrt(DK) into Q).
__global__ void k_transpose_w(const float* __restrict__ Wq, const float* __restrict__ Wk,
                              const float* __restrict__ Wv, const float* __restrict__ Wo,
                              unsigned short* __restrict__ wt_qkv, unsigned short* __restrict__ wt_o) {
  __shared__ float tls[64][65];
  int bid = blockIdx.x;
  int mat = bid >> 8;
  int tile = bid & 255;
  int tk = tile >> 4, tn = tile & 15;
  const float* W = (mat == 0) ? Wq : (mat == 1) ? Wk : (mat == 2) ? Wv : Wo;
  int t = threadIdx.x;
  int lr = t >> 2;
  int lc0 = (t & 3) * 16;
  const float* src = W + (size_t)(tk * 64 + lr) * 1024 + tn * 64 + lc0;
#pragma unroll
  for (int j = 0; j < 16; j += 4) {
    float4 v = *(const float4*)(src + j);
    tls[lr][lc0 + j + 0] = v.x; tls[lr][lc0 + j + 1] = v.y;
    tls[lr][lc0 + j + 2] = v.z; tls[lr][lc0 + j + 3] = v.w;
  }
  __syncthreads();
  float scale = (mat == 0) ? 0.125f : 1.0f;
  int nr = t >> 2, kc0 = (t & 3) * 16;
  unsigned short* dst = ((mat < 3) ? (wt_qkv + (size_t)(mat * 1024 + tn * 64 + nr) * 1024)
                                   : (wt_o + (size_t)(tn * 64 + nr) * 1024)) + tk * 64 + kc0;
  us8v o0, o1;
#pragma unroll
  for (int j = 0; j < 8; j++) o0[j] = f2bf(tls[kc0 + j][nr] * scale);
#pragma unroll
  for (int j = 0; j < 8; j++) o1[j] = f2bf(tls[kc0 + 8 + j][nr] * scale);
  *(us8v*)(dst) = o0;
  *(us8v*)(dst + 8) = o1;
}

// ----------------------------------------------------------------- bf16 GEMM
// C[M,N] = A[M,K] * Bt[N,K]^T.  128x128 tile, BK=64, 4 waves (2x2 of 64x64).
// global_load_lds(16B) staging, source-side XOR swizzle granule^(row&7).
// MODE 0: QKV epilogue (bf16; n<2048 -> qklin, else -> vt transposed scatter)
// MODE 1: out = val + bias  (fp32)
template <int MODE>
__global__ __launch_bounds__(256) void k_gemm(const unsigned short* __restrict__ A,
                                              const unsigned short* __restrict__ Bt,
                                              unsigned short* __restrict__ qklin,
                                              unsigned short* __restrict__ vt,
                                              const float* __restrict__ bias,
                                              float* __restrict__ out) {
  __shared__ unsigned short lds_a[128 * 64];
  __shared__ unsigned short lds_b[128 * 64];
  const int K = 1024;
  int m0 = blockIdx.y * 128, n0 = blockIdx.x * 128;
  int tid = threadIdx.x, lane = tid & 63, w = tid >> 6;
  int wm = w >> 1, wn = w & 1;
  int g = lane >> 4, c0 = lane & 15;
  int rrel = lane >> 3;      // staging row within 8-row group (= row&7)
  int gran = lane & 7;       // staging 16B granule
  f4v acc[4][4];
#pragma unroll
  for (int mi = 0; mi < 4; mi++)
#pragma unroll
    for (int ni = 0; ni < 4; ni++) acc[mi][ni] = (f4v){0.f, 0.f, 0.f, 0.f};

  for (int kt = 0; kt < K / 64; ++kt) {
#pragma unroll
    for (int i = 0; i < 4; i++) {
      int r = 32 * w + 8 * i + rrel;
      gload16(A + (size_t)(m0 + r) * K + kt * 64 + 8 * (gran ^ rrel),
              (void*)(lds_a + (32 * w + 8 * i) * 64));
      gload16(Bt + (size_t)(n0 + r) * K + kt * 64 + 8 * (gran ^ rrel),
              (void*)(lds_b + (32 * w + 8 * i) * 64));
    }
    __syncthreads();
#pragma unroll
    for (int c = 0; c < 2; c++) {
      s8v af[4], bfr[4];
#pragma unroll
      for (int mi = 0; mi < 4; mi++) {
        int row = 64 * wm + 16 * mi + c0;
        af[mi] = *(const s8v*)(lds_a + row * 64 + 8 * ((g + 4 * c) ^ (c0 & 7)));
      }
#pragma unroll
      for (int ni = 0; ni < 4; ni++) {
        int row = 64 * wn + 16 * ni + c0;
        bfr[ni] = *(const s8v*)(lds_b + row * 64 + 8 * ((g + 4 * c) ^ (c0 & 7)));
      }
#pragma unroll
      for (int mi = 0; mi < 4; mi++)
#pragma unroll
        for (int ni = 0; ni < 4; ni++)
          acc[mi][ni] = __builtin_amdgcn_mfma_f32_16x16x32_bf16(af[mi], bfr[ni], acc[mi][ni], 0, 0, 0);
    }
    __syncthreads();
  }

#pragma unroll
  for (int mi = 0; mi < 4; mi++)
#pragma unroll
    for (int ni = 0; ni < 4; ni++)
#pragma unroll
      for (int r = 0; r < 4; r++) {
        int m = m0 + 64 * wm + 16 * mi + 4 * g + r;
        int n = n0 + 64 * wn + 16 * ni + c0;
        float v = acc[mi][ni][r];
        if (MODE == 0) {
          unsigned short hv = f2bf(v);
          if (n < 2048) {
            qklin[(size_t)m * 2048 + n] = hv;
          } else {
            int b = m >> 11, s = m & 2047;
            int hh = (n - 2048) >> 6, dk = n & 63;
            vt[(size_t)((b * 16 + hh) * 64 + dk) * 2048 + s] = hv;
          }
        } else {
          out[(size_t)m * 1024 + n] = v + bias[n];
        }
      }
}

// ----------------------------------------------------------------- V row mean
__global__ void k_vmean(const unsigned short* __restrict__ vt, float* __restrict__ vmean) {
  int row = blockIdx.x * 4 + (threadIdx.x >> 6);
  int lane = threadIdx.x & 63;
  const unsigned short* p = vt + (size_t)row * 2048 + lane * 32;
  float s = 0.f;
#pragma unroll
  for (int j = 0; j < 32; j += 8) {
    us8v v = *(const us8v*)(p + j);
#pragma unroll
    for (int e = 0; e < 8; e++) s += bf2f(v[e]);
  }
#pragma unroll
  for (int m = 1; m < 64; m <<= 1) s += __shfl_xor(s, m);
  if (lane == 0) vmean[row] = s * (1.0f / 2048.0f);
}

// ------------------------------------------------------------ flash attention
// WG = 256 thr = 4 independent waves; wave handles 16 q-rows of a 64-row tile.
// Q/K read from qklin [4096][2048] (Q cols 0..1023 pre-scaled, K cols 1024..2047),
// V from vt [bh*64+dk][s].  Online softmax; P relayout via per-wave swizzled LDS.
__global__ __launch_bounds__(256) void k_attn(const unsigned short* __restrict__ qklin,
                                              const unsigned short* __restrict__ vt,
                                              const int* __restrict__ kpm,
                                              const float* __restrict__ vmean,
                                              unsigned short* __restrict__ ctx) {
  __shared__ unsigned short p_lds[4][16 * 64];
  int wg = blockIdx.x;
  int qt = wg & 31, bh = wg >> 5;
  int b = bh >> 4, h = bh & 15;
  int tid = threadIdx.x, lane = tid & 63, w = tid >> 6;
  int g = lane >> 4, c0 = lane & 15;
  int q0 = qt * 64 + w * 16;
  unsigned short* pl = p_lds[w];

  const unsigned short* qbase = qklin + (size_t)(b * NS + q0 + c0) * 2048 + h * 64 + 8 * g;
  s8v qf0 = *(const s8v*)(qbase);
  s8v qf1 = *(const s8v*)(qbase + 32);

  f4v cacc[4];
#pragma unroll
  for (int d = 0; d < 4; d++) cacc[d] = (f4v){0.f, 0.f, 0.f, 0.f};
  float m_r[4], l_r[4];
#pragma unroll
  for (int r = 0; r < 4; r++) { m_r[r] = -1e30f; l_r[r] = 0.f; }

  int nkt = qt + 1;
  for (int it = 0; it < nkt; ++it) {
    int kb = it * 64;
    // ---- scores: 4 key-subtiles of 16
    f4v sacc[4];
    int kpmv[4];
#pragma unroll
    for (int t = 0; t < 4; t++) {
      const unsigned short* kbase =
          qklin + (size_t)(b * NS + kb + 16 * t + c0) * 2048 + 1024 + h * 64 + 8 * g;
      s8v kf0 = *(const s8v*)(kbase);
      s8v kf1 = *(const s8v*)(kbase + 32);
      f4v z = (f4v){0.f, 0.f, 0.f, 0.f};
      z = __builtin_amdgcn_mfma_f32_16x16x32_bf16(qf0, kf0, z, 0, 0, 0);
      z = __builtin_amdgcn_mfma_f32_16x16x32_bf16(qf1, kf1, z, 0, 0, 0);
      sacc[t] = z;
      kpmv[t] = kpm[b * NS + kb + 16 * t + c0];
    }
    // ---- mask + online softmax (rows = 4g+r, spread over 16-lane group)
    float pv[4][4];
#pragma unroll
    for (int r = 0; r < 4; r++) {
      int qrow = q0 + 4 * g + r;
      float mx = -1e30f;
#pragma unroll
      for (int t = 0; t < 4; t++) {
        int key = kb + 16 * t + c0;
        float s = sacc[t][r];
        bool valid = (key <= qrow) && (kpmv[t] == 0);
        s = valid ? s : -1e30f;
        pv[t][r] = s;
        mx = fmaxf(mx, s);
      }
      mx = fmaxf(mx, __shfl_xor(mx, 1));
      mx = fmaxf(mx, __shfl_xor(mx, 2));
      mx = fmaxf(mx, __shfl_xor(mx, 4));
      mx = fmaxf(mx, __shfl_xor(mx, 8));
      float mnew = fmaxf(m_r[r], mx);
      float a = __expf(m_r[r] - mnew);
      float rs = 0.f;
#pragma unroll
      for (int t = 0; t < 4; t++) {
        float s = pv[t][r];
        float p = (s > -1e29f) ? __expf(s - mnew) : 0.f;
        pv[t][r] = p;
        rs += p;
      }
      rs += __shfl_xor(rs, 1);
      rs += __shfl_xor(rs, 2);
      rs += __shfl_xor(rs, 4);
      rs += __shfl_xor(rs, 8);
      l_r[r] = l_r[r] * a + rs;
      m_r[r] = mnew;
#pragma unroll
      for (int d = 0; d < 4; d++) cacc[d][r] *= a;
    }
    // ---- P -> LDS (bf16, XOR-swizzled rows)
#pragma unroll
    for (int t = 0; t < 4; t++)
#pragma unroll
      for (int r = 0; r < 4; r++) {
        int q = 4 * g + r;
        int off = q * 128 + (16 * t + c0) * 2;
        off ^= (q & 7) << 4;
        *(unsigned short*)((char*)pl + off) = f2bf(pv[t][r]);
      }
    asm volatile("s_waitcnt lgkmcnt(0)" ::: "memory");
    __builtin_amdgcn_sched_barrier(0);
    // ---- PV
#pragma unroll
    for (int c = 0; c < 2; c++) {
      int off = c0 * 128 + 16 * g + 64 * c;
      off ^= (c0 & 7) << 4;
      s8v pf = *(const s8v*)((const char*)pl + off);
#pragma unroll
      for (int d = 0; d < 4; d++) {
        const unsigned short* vb =
            vt + (size_t)(bh * 64 + 16 * d + c0) * 2048 + kb + 32 * c + 8 * g;
        s8v vf = *(const s8v*)vb;
        cacc[d] = __builtin_amdgcn_mfma_f32_16x16x32_bf16(pf, vf, cacc[d], 0, 0, 0);
      }
    }
  }
  // ---- epilogue: ctx = cacc / l  (or vmean fallback for fully-masked rows)
#pragma unroll
  for (int d = 0; d < 4; d++)
#pragma unroll
    for (int r = 0; r < 4; r++) {
      int q = q0 + 4 * g + r;
      float l = l_r[r];
      float v = (l > 0.f) ? cacc[d][r] / l : vmean[bh * 64 + 16 * d + c0];
      ctx[(size_t)(b * NS + q) * ND + h * 64 + 16 * d + c0] = f2bf(v);
    }
}

// ----------------------------------------------------------------------------
extern "C" void kernel_launch(void* const* d_in, const int* in_sizes, int n_in,
                              void* d_out, int out_size, void* d_ws, size_t ws_size,
                              hipStream_t stream) {
  const float* x  = (const float*)d_in[0];
  // d_in[1] = additive causal mask (structure reimplemented, unused)
  const int* kpm  = (const int*)d_in[2];
  const float* Wq = (const float*)d_in[3];
  const float* Wk = (const float*)d_in[4];
  const float* Wv = (const float*)d_in[5];
  const float* Wo = (const float*)d_in[6];
  const float* bo = (const float*)d_in[7];

  char* ws = (char*)d_ws;
  unsigned short* xbf   = (unsigned short*)(ws);                      // 8 MB (reused as ctx)
  unsigned short* wtqkv = (unsigned short*)(ws + 8u * 1024 * 1024);   // 6 MB
  unsigned short* wto   = (unsigned short*)(ws + 14u * 1024 * 1024);  // 2 MB
  unsigned short* vt    = (unsigned short*)(ws + 16u * 1024 * 1024);  // 8 MB
  float* vmean          = (float*)(ws + 24u * 1024 * 1024);           // 8 KB
  unsigned short* ctx   = xbf;                 // alias: xbf dead after QKV GEMM
  unsigned short* qklin = (unsigned short*)d_out;  // d_out as scratch until final GEMM

  k_convert_x<<<4096, 256, 0, stream>>>(x, xbf);
  k_transpose_w<<<1024, 256, 0, stream>>>(Wq, Wk, Wv, Wo, wtqkv, wto);
  dim3 g0(24, 32);
  k_gemm<0><<<g0, 256, 0, stream>>>(xbf, wtqkv, qklin, vt, nullptr, nullptr);
  k_vmean<<<512, 256, 0, stream>>>(vt, vmean);
  k_attn<<<1024, 256, 0, stream>>>(qklin, vt, kpm, vmean, ctx);
  dim3 g1(8, 32);
  k_gemm<1><<<g1, 256, 0, stream>>>(ctx, wto, nullptr, nullptr, bo, (float*)d_out);
}

// Round 4
// 181.552 us; speedup vs baseline: 1.8712x; 1.8712x over previous
//
#include <hip/hip_runtime.h>
#include <stdint.h>

#define NB 2
#define NS 2048
#define ND 1024
#define NH 16
#define NDK 64

typedef __attribute__((ext_vector_type(8))) short s8v;
typedef __attribute__((ext_vector_type(4))) float f4v;
typedef __attribute__((ext_vector_type(4))) unsigned short us4v;
typedef __attribute__((ext_vector_type(8))) unsigned short us8v;

__device__ __forceinline__ unsigned short f2bf(float f) {
  uint32_t u = __builtin_bit_cast(uint32_t, f);
  u = (u + 0x7fffu + ((u >> 16) & 1u)) >> 16;
  return (unsigned short)u;
}
__device__ __forceinline__ float bf2f(unsigned short h) {
  uint32_t u = ((uint32_t)h) << 16;
  return __builtin_bit_cast(float, u);
}

__device__ __forceinline__ void gload16(const void* g, void* l) {
  __builtin_amdgcn_global_load_lds(
      (const __attribute__((address_space(1))) void*)g,
      (__attribute__((address_space(3))) void*)l, 16, 0, 0);
}

// ---------------------------------------------------------------- convert x
__global__ void k_convert_x(const float* __restrict__ x, unsigned short* __restrict__ xbf) {
  int i = (blockIdx.x * 256 + threadIdx.x) * 4;
  float4 v = *(const float4*)(x + i);
  us4v o;
  o[0] = f2bf(v.x); o[1] = f2bf(v.y); o[2] = f2bf(v.z); o[3] = f2bf(v.w);
  *(us4v*)(xbf + i) = o;
}

// ------------------------------------------------- transpose+convert weights
__global__ void k_transpose_w(const float* __restrict__ Wq, const float* __restrict__ Wk,
                              const float* __restrict__ Wv, const float* __restrict__ Wo,
                              unsigned short* __restrict__ wt_qkv, unsigned short* __restrict__ wt_o) {
  __shared__ float tls[64][65];
  int bid = blockIdx.x;
  int mat = bid >> 8;
  int tile = bid & 255;
  int tk = tile >> 4, tn = tile & 15;
  const float* W = (mat == 0) ? Wq : (mat == 1) ? Wk : (mat == 2) ? Wv : Wo;
  int t = threadIdx.x;
  int lr = t >> 2;
  int lc0 = (t & 3) * 16;
  const float* src = W + (size_t)(tk * 64 + lr) * 1024 + tn * 64 + lc0;
#pragma unroll
  for (int j = 0; j < 16; j += 4) {
    float4 v = *(const float4*)(src + j);
    tls[lr][lc0 + j + 0] = v.x; tls[lr][lc0 + j + 1] = v.y;
    tls[lr][lc0 + j + 2] = v.z; tls[lr][lc0 + j + 3] = v.w;
  }
  __syncthreads();
  float scale = (mat == 0) ? 0.125f : 1.0f;
  int nr = t >> 2, kc0 = (t & 3) * 16;
  unsigned short* dst = ((mat < 3) ? (wt_qkv + (size_t)(mat * 1024 + tn * 64 + nr) * 1024)
                                   : (wt_o + (size_t)(tn * 64 + nr) * 1024)) + tk * 64 + kc0;
  us8v o0, o1;
#pragma unroll
  for (int j = 0; j < 8; j++) o0[j] = f2bf(tls[kc0 + j][nr] * scale);
#pragma unroll
  for (int j = 0; j < 8; j++) o1[j] = f2bf(tls[kc0 + 8 + j][nr] * scale);
  *(us8v*)(dst) = o0;
  *(us8v*)(dst + 8) = o1;
}

// ----------------------------------------------------------------- bf16 GEMM
template <int MODE>
__global__ __launch_bounds__(256) void k_gemm(const unsigned short* __restrict__ A,
                                              const unsigned short* __restrict__ Bt,
                                              unsigned short* __restrict__ qklin,
                                              unsigned short* __restrict__ vt,
                                              const float* __restrict__ bias,
                                              float* __restrict__ out) {
  __shared__ unsigned short lds_a[128 * 64];
  __shared__ unsigned short lds_b[128 * 64];
  const int K = 1024;
  int m0 = blockIdx.y * 128, n0 = blockIdx.x * 128;
  int tid = threadIdx.x, lane = tid & 63, w = tid >> 6;
  int wm = w >> 1, wn = w & 1;
  int g = lane >> 4, c0 = lane & 15;
  int rrel = lane >> 3;
  int gran = lane & 7;
  f4v acc[4][4];
#pragma unroll
  for (int mi = 0; mi < 4; mi++)
#pragma unroll
    for (int ni = 0; ni < 4; ni++) acc[mi][ni] = (f4v){0.f, 0.f, 0.f, 0.f};

  for (int kt = 0; kt < K / 64; ++kt) {
#pragma unroll
    for (int i = 0; i < 4; i++) {
      int r = 32 * w + 8 * i + rrel;
      gload16(A + (size_t)(m0 + r) * K + kt * 64 + 8 * (gran ^ rrel),
              (void*)(lds_a + (32 * w + 8 * i) * 64));
      gload16(Bt + (size_t)(n0 + r) * K + kt * 64 + 8 * (gran ^ rrel),
              (void*)(lds_b + (32 * w + 8 * i) * 64));
    }
    __syncthreads();
#pragma unroll
    for (int c = 0; c < 2; c++) {
      s8v af[4], bfr[4];
#pragma unroll
      for (int mi = 0; mi < 4; mi++) {
        int row = 64 * wm + 16 * mi + c0;
        af[mi] = *(const s8v*)(lds_a + row * 64 + 8 * ((g + 4 * c) ^ (c0 & 7)));
      }
#pragma unroll
      for (int ni = 0; ni < 4; ni++) {
        int row = 64 * wn + 16 * ni + c0;
        bfr[ni] = *(const s8v*)(lds_b + row * 64 + 8 * ((g + 4 * c) ^ (c0 & 7)));
      }
#pragma unroll
      for (int mi = 0; mi < 4; mi++)
#pragma unroll
        for (int ni = 0; ni < 4; ni++)
          acc[mi][ni] = __builtin_amdgcn_mfma_f32_16x16x32_bf16(af[mi], bfr[ni], acc[mi][ni], 0, 0, 0);
    }
    __syncthreads();
  }

#pragma unroll
  for (int mi = 0; mi < 4; mi++)
#pragma unroll
    for (int ni = 0; ni < 4; ni++)
#pragma unroll
      for (int r = 0; r < 4; r++) {
        int m = m0 + 64 * wm + 16 * mi + 4 * g + r;
        int n = n0 + 64 * wn + 16 * ni + c0;
        float v = acc[mi][ni][r];
        if (MODE == 0) {
          unsigned short hv = f2bf(v);
          if (n < 2048) {
            qklin[(size_t)m * 2048 + n] = hv;
          } else {
            int b = m >> 11, s = m & 2047;
            int hh = (n - 2048) >> 6, dk = n & 63;
            vt[(size_t)((b * 16 + hh) * 64 + dk) * 2048 + s] = hv;
          }
        } else {
          out[(size_t)m * 1024 + n] = v + bias[n];
        }
      }
}

// ----------------------------------------------------------------- V row mean
__global__ void k_vmean(const unsigned short* __restrict__ vt, float* __restrict__ vmean) {
  int row = blockIdx.x * 4 + (threadIdx.x >> 6);
  int lane = threadIdx.x & 63;
  const unsigned short* p = vt + (size_t)row * 2048 + lane * 32;
  float s = 0.f;
#pragma unroll
  for (int j = 0; j < 32; j += 8) {
    us8v v = *(const us8v*)(p + j);
#pragma unroll
    for (int e = 0; e < 8; e++) s += bf2f(v[e]);
  }
#pragma unroll
  for (int m = 1; m < 64; m <<= 1) s += __shfl_xor(s, m);
  if (lane == 0) vmean[row] = s * (1.0f / 2048.0f);
}

// ------------------------------------------------------------ flash attention
// WG = 4 waves, all on the SAME 64-row q-tile (wave w -> rows q0..q0+15).
// wg = qt*32 + bh  =>  wg%8 == bh%8: all q-tiles of a head land on one XCD.
// K staged in LDS double-buffered (K(it+1) staged during iter it); V staged
// single-buffered at iter start, consumed in PV after the barrier.  Staging
// uses global_load_lds w=16 with source-side XOR swizzle granule^(row&7)
// (same proven scheme as k_gemm); fragment ds_reads apply the same XOR.
__global__ __launch_bounds__(256) void k_attn(const unsigned short* __restrict__ qklin,
                                              const unsigned short* __restrict__ vt,
                                              const int* __restrict__ kpm,
                                              const float* __restrict__ vmean,
                                              unsigned short* __restrict__ ctx) {
  __shared__ unsigned short lds_k[2][64 * 64];
  __shared__ unsigned short lds_v[64 * 64];
  __shared__ unsigned short p_lds[4][16 * 64];
  int wg = blockIdx.x;
  int qt = wg >> 5, bh = wg & 31;
  int b = bh >> 4, h = bh & 15;
  int tid = threadIdx.x, lane = tid & 63, w = tid >> 6;
  int g = lane >> 4, c0 = lane & 15;
  int q0 = qt * 64 + w * 16;
  unsigned short* pl = p_lds[w];
  int rrel = lane >> 3, gran = lane & 7;

  const unsigned short* ksrc0 = qklin + (size_t)(b * NS) * 2048 + 1024 + h * 64;
  const unsigned short* vsrc0 = vt + (size_t)(bh * 64) * 2048;

  const unsigned short* qbase = qklin + (size_t)(b * NS + q0 + c0) * 2048 + h * 64 + 8 * g;
  s8v qf0 = *(const s8v*)(qbase);
  s8v qf1 = *(const s8v*)(qbase + 32);

  f4v cacc[4];
#pragma unroll
  for (int d = 0; d < 4; d++) cacc[d] = (f4v){0.f, 0.f, 0.f, 0.f};
  float m_r[4], l_r[4];
#pragma unroll
  for (int r = 0; r < 4; r++) { m_r[r] = -1e30f; l_r[r] = 0.f; }

  // prologue: stage K tile 0
#pragma unroll
  for (int i = 0; i < 2; i++) {
    int r = 16 * w + 8 * i + rrel;
    gload16(ksrc0 + (size_t)r * 2048 + 8 * (gran ^ rrel),
            (void*)(lds_k[0] + (16 * w + 8 * i) * 64));
  }
  __syncthreads();

  int nkt = qt + 1;
  for (int it = 0; it < nkt; ++it) {
    int kb = it * 64;
    int cur = it & 1;
    // ---- stage V(it) (consumed in PV this iter, after the barrier)
#pragma unroll
    for (int i = 0; i < 2; i++) {
      int r = 16 * w + 8 * i + rrel;
      gload16(vsrc0 + (size_t)r * 2048 + kb + 8 * (gran ^ rrel),
              (void*)(lds_v + (16 * w + 8 * i) * 64));
    }
    // ---- stage K(it+1) into the other buffer
    if (it < qt) {
#pragma unroll
      for (int i = 0; i < 2; i++) {
        int r = 16 * w + 8 * i + rrel;
        gload16(ksrc0 + (size_t)(kb + 64 + r) * 2048 + 8 * (gran ^ rrel),
                (void*)(lds_k[cur ^ 1] + (16 * w + 8 * i) * 64));
      }
    }
    // ---- key-padding mask + scores from lds_k[cur]
    f4v sacc[4];
    int kpmv[4];
#pragma unroll
    for (int t = 0; t < 4; t++) {
      int row = 16 * t + c0;
      s8v kf0 = *(const s8v*)(lds_k[cur] + row * 64 + 8 * (g ^ (c0 & 7)));
      s8v kf1 = *(const s8v*)(lds_k[cur] + row * 64 + 8 * ((4 + g) ^ (c0 & 7)));
      f4v z = (f4v){0.f, 0.f, 0.f, 0.f};
      z = __builtin_amdgcn_mfma_f32_16x16x32_bf16(qf0, kf0, z, 0, 0, 0);
      z = __builtin_amdgcn_mfma_f32_16x16x32_bf16(qf1, kf1, z, 0, 0, 0);
      sacc[t] = z;
      kpmv[t] = kpm[b * NS + kb + 16 * t + c0];
    }
    // ---- mask + online softmax
    float pv[4][4];
#pragma unroll
    for (int r = 0; r < 4; r++) {
      int qrow = q0 + 4 * g + r;
      float mx = -1e30f;
#pragma unroll
      for (int t = 0; t < 4; t++) {
        int key = kb + 16 * t + c0;
        float s = sacc[t][r];
        bool valid = (key <= qrow) && (kpmv[t] == 0);
        s = valid ? s : -1e30f;
        pv[t][r] = s;
        mx = fmaxf(mx, s);
      }
      mx = fmaxf(mx, __shfl_xor(mx, 1));
      mx = fmaxf(mx, __shfl_xor(mx, 2));
      mx = fmaxf(mx, __shfl_xor(mx, 4));
      mx = fmaxf(mx, __shfl_xor(mx, 8));
      float mnew = fmaxf(m_r[r], mx);
      float a = __expf(m_r[r] - mnew);
      float rs = 0.f;
#pragma unroll
      for (int t = 0; t < 4; t++) {
        float s = pv[t][r];
        float p = (s > -1e29f) ? __expf(s - mnew) : 0.f;
        pv[t][r] = p;
        rs += p;
      }
      rs += __shfl_xor(rs, 1);
      rs += __shfl_xor(rs, 2);
      rs += __shfl_xor(rs, 4);
      rs += __shfl_xor(rs, 8);
      l_r[r] = l_r[r] * a + rs;
      m_r[r] = mnew;
#pragma unroll
      for (int d = 0; d < 4; d++) cacc[d][r] *= a;
    }
    // ---- P -> LDS (bf16, XOR-swizzled rows)
#pragma unroll
    for (int t = 0; t < 4; t++)
#pragma unroll
      for (int r = 0; r < 4; r++) {
        int q = 4 * g + r;
        int off = q * 128 + (16 * t + c0) * 2;
        off ^= (q & 7) << 4;
        *(unsigned short*)((char*)pl + off) = f2bf(pv[t][r]);
      }
    // publishes: V(it) + K(it+1) staging (vmcnt drain) and P writes (lgkm)
    __syncthreads();
    // ---- PV from lds_v
#pragma unroll
    for (int c = 0; c < 2; c++) {
      int off = c0 * 128 + 16 * g + 64 * c;
      off ^= (c0 & 7) << 4;
      s8v pf = *(const s8v*)((const char*)pl + off);
#pragma unroll
      for (int d = 0; d < 4; d++) {
        int row = 16 * d + c0;
        s8v vf = *(const s8v*)(lds_v + row * 64 + 8 * ((4 * c + g) ^ (c0 & 7)));
        cacc[d] = __builtin_amdgcn_mfma_f32_16x16x32_bf16(pf, vf, cacc[d], 0, 0, 0);
      }
    }
    // all waves done reading lds_v / lds_k[cur] before next-iter staging
    __syncthreads();
  }
  // ---- epilogue
#pragma unroll
  for (int d = 0; d < 4; d++)
#pragma unroll
    for (int r = 0; r < 4; r++) {
      int q = q0 + 4 * g + r;
      float l = l_r[r];
      float v = (l > 0.f) ? cacc[d][r] / l : vmean[bh * 64 + 16 * d + c0];
      ctx[(size_t)(b * NS + q) * ND + h * 64 + 16 * d + c0] = f2bf(v);
    }
}

// ----------------------------------------------------------------------------
extern "C" void kernel_launch(void* const* d_in, const int* in_sizes, int n_in,
                              void* d_out, int out_size, void* d_ws, size_t ws_size,
                              hipStream_t stream) {
  const float* x  = (const float*)d_in[0];
  const int* kpm  = (const int*)d_in[2];
  const float* Wq = (const float*)d_in[3];
  const float* Wk = (const float*)d_in[4];
  const float* Wv = (const float*)d_in[5];
  const float* Wo = (const float*)d_in[6];
  const float* bo = (const float*)d_in[7];

  char* ws = (char*)d_ws;
  unsigned short* xbf   = (unsigned short*)(ws);
  unsigned short* wtqkv = (unsigned short*)(ws + 8u * 1024 * 1024);
  unsigned short* wto   = (unsigned short*)(ws + 14u * 1024 * 1024);
  unsigned short* vt    = (unsigned short*)(ws + 16u * 1024 * 1024);
  float* vmean          = (float*)(ws + 24u * 1024 * 1024);
  unsigned short* ctx   = xbf;
  unsigned short* qklin = (unsigned short*)d_out;

  k_convert_x<<<4096, 256, 0, stream>>>(x, xbf);
  k_transpose_w<<<1024, 256, 0, stream>>>(Wq, Wk, Wv, Wo, wtqkv, wto);
  dim3 g0(24, 32);
  k_gemm<0><<<g0, 256, 0, stream>>>(xbf, wtqkv, qklin, vt, nullptr, nullptr);
  k_vmean<<<512, 256, 0, stream>>>(vt, vmean);
  k_attn<<<1024, 256, 0, stream>>>(qklin, vt, kpm, vmean, ctx);
  dim3 g1(8, 32);
  k_gemm<1><<<g1, 256, 0, stream>>>(ctx, wto, nullptr, nullptr, bo, (float*)d_out);
}

// Round 5
// 146.957 us; speedup vs baseline: 2.3116x; 1.2354x over previous
//
#include <hip/hip_runtime.h>
#include <stdint.h>

#define NB 2
#define NS 2048
#define ND 1024
#define NH 16
#define NDK 64

typedef __attribute__((ext_vector_type(8))) short s8v;
typedef __attribute__((ext_vector_type(4))) float f4v;
typedef __attribute__((ext_vector_type(4))) unsigned short us4v;
typedef __attribute__((ext_vector_type(8))) unsigned short us8v;
typedef __attribute__((ext_vector_type(2))) uint32_t u2v;

__device__ __forceinline__ unsigned short f2bf(float f) {
  uint32_t u = __builtin_bit_cast(uint32_t, f);
  u = (u + 0x7fffu + ((u >> 16) & 1u)) >> 16;
  return (unsigned short)u;
}
__device__ __forceinline__ float bf2f(unsigned short h) {
  uint32_t u = ((uint32_t)h) << 16;
  return __builtin_bit_cast(float, u);
}
// packed f32x2 -> bf16x2 (lo -> bits[15:0]), RNE
__device__ __forceinline__ uint32_t cvtpk(float lo, float hi) {
  uint32_t r;
  asm("v_cvt_pk_bf16_f32 %0, %1, %2" : "=v"(r) : "v"(lo), "v"(hi));
  return r;
}

__device__ __forceinline__ void gload16(const void* g, void* l) {
  __builtin_amdgcn_global_load_lds(
      (const __attribute__((address_space(1))) void*)g,
      (__attribute__((address_space(3))) void*)l, 16, 0, 0);
}

// ---------------------------------------------------------------- convert x
__global__ void k_convert_x(const float* __restrict__ x, unsigned short* __restrict__ xbf) {
  int i = (blockIdx.x * 256 + threadIdx.x) * 4;
  float4 v = *(const float4*)(x + i);
  us4v o;
  o[0] = f2bf(v.x); o[1] = f2bf(v.y); o[2] = f2bf(v.z); o[3] = f2bf(v.w);
  *(us4v*)(xbf + i) = o;
}

// ------------------------------------------------- transpose+convert weights
__global__ void k_transpose_w(const float* __restrict__ Wq, const float* __restrict__ Wk,
                              const float* __restrict__ Wv, const float* __restrict__ Wo,
                              unsigned short* __restrict__ wt_qkv, unsigned short* __restrict__ wt_o) {
  __shared__ float tls[64][65];
  int bid = blockIdx.x;
  int mat = bid >> 8;
  int tile = bid & 255;
  int tk = tile >> 4, tn = tile & 15;
  const float* W = (mat == 0) ? Wq : (mat == 1) ? Wk : (mat == 2) ? Wv : Wo;
  int t = threadIdx.x;
  int lr = t >> 2;
  int lc0 = (t & 3) * 16;
  const float* src = W + (size_t)(tk * 64 + lr) * 1024 + tn * 64 + lc0;
#pragma unroll
  for (int j = 0; j < 16; j += 4) {
    float4 v = *(const float4*)(src + j);
    tls[lr][lc0 + j + 0] = v.x; tls[lr][lc0 + j + 1] = v.y;
    tls[lr][lc0 + j + 2] = v.z; tls[lr][lc0 + j + 3] = v.w;
  }
  __syncthreads();
  float scale = (mat == 0) ? 0.125f : 1.0f;
  int nr = t >> 2, kc0 = (t & 3) * 16;
  unsigned short* dst = ((mat < 3) ? (wt_qkv + (size_t)(mat * 1024 + tn * 64 + nr) * 1024)
                                   : (wt_o + (size_t)(tn * 64 + nr) * 1024)) + tk * 64 + kc0;
  us8v o0, o1;
#pragma unroll
  for (int j = 0; j < 8; j++) o0[j] = f2bf(tls[kc0 + j][nr] * scale);
#pragma unroll
  for (int j = 0; j < 8; j++) o1[j] = f2bf(tls[kc0 + 8 + j][nr] * scale);
  *(us8v*)(dst) = o0;
  *(us8v*)(dst + 8) = o1;
}

// ----------------------------------------------------------------- bf16 GEMM
template <int MODE>
__global__ __launch_bounds__(256) void k_gemm(const unsigned short* __restrict__ A,
                                              const unsigned short* __restrict__ Bt,
                                              unsigned short* __restrict__ qklin,
                                              unsigned short* __restrict__ vt,
                                              const float* __restrict__ bias,
                                              float* __restrict__ out) {
  __shared__ unsigned short lds_a[128 * 64];
  __shared__ unsigned short lds_b[128 * 64];
  const int K = 1024;
  int m0 = blockIdx.y * 128, n0 = blockIdx.x * 128;
  int tid = threadIdx.x, lane = tid & 63, w = tid >> 6;
  int wm = w >> 1, wn = w & 1;
  int g = lane >> 4, c0 = lane & 15;
  int rrel = lane >> 3;
  int gran = lane & 7;
  f4v acc[4][4];
#pragma unroll
  for (int mi = 0; mi < 4; mi++)
#pragma unroll
    for (int ni = 0; ni < 4; ni++) acc[mi][ni] = (f4v){0.f, 0.f, 0.f, 0.f};

  for (int kt = 0; kt < K / 64; ++kt) {
#pragma unroll
    for (int i = 0; i < 4; i++) {
      int r = 32 * w + 8 * i + rrel;
      gload16(A + (size_t)(m0 + r) * K + kt * 64 + 8 * (gran ^ rrel),
              (void*)(lds_a + (32 * w + 8 * i) * 64));
      gload16(Bt + (size_t)(n0 + r) * K + kt * 64 + 8 * (gran ^ rrel),
              (void*)(lds_b + (32 * w + 8 * i) * 64));
    }
    __syncthreads();
#pragma unroll
    for (int c = 0; c < 2; c++) {
      s8v af[4], bfr[4];
#pragma unroll
      for (int mi = 0; mi < 4; mi++) {
        int row = 64 * wm + 16 * mi + c0;
        af[mi] = *(const s8v*)(lds_a + row * 64 + 8 * ((g + 4 * c) ^ (c0 & 7)));
      }
#pragma unroll
      for (int ni = 0; ni < 4; ni++) {
        int row = 64 * wn + 16 * ni + c0;
        bfr[ni] = *(const s8v*)(lds_b + row * 64 + 8 * ((g + 4 * c) ^ (c0 & 7)));
      }
#pragma unroll
      for (int mi = 0; mi < 4; mi++)
#pragma unroll
        for (int ni = 0; ni < 4; ni++)
          acc[mi][ni] = __builtin_amdgcn_mfma_f32_16x16x32_bf16(af[mi], bfr[ni], acc[mi][ni], 0, 0, 0);
    }
    __syncthreads();
  }

#pragma unroll
  for (int mi = 0; mi < 4; mi++)
#pragma unroll
    for (int ni = 0; ni < 4; ni++)
#pragma unroll
      for (int r = 0; r < 4; r++) {
        int m = m0 + 64 * wm + 16 * mi + 4 * g + r;
        int n = n0 + 64 * wn + 16 * ni + c0;
        float v = acc[mi][ni][r];
        if (MODE == 0) {
          unsigned short hv = f2bf(v);
          if (n < 2048) {
            qklin[(size_t)m * 2048 + n] = hv;
          } else {
            int b = m >> 11, s = m & 2047;
            int hh = (n - 2048) >> 6, dk = n & 63;
            vt[(size_t)((b * 16 + hh) * 64 + dk) * 2048 + s] = hv;
          }
        } else {
          out[(size_t)m * 1024 + n] = v + bias[n];
        }
      }
}

// ----------------------------------------------------------------- V row mean
__global__ void k_vmean(const unsigned short* __restrict__ vt, float* __restrict__ vmean) {
  int row = blockIdx.x * 4 + (threadIdx.x >> 6);
  int lane = threadIdx.x & 63;
  const unsigned short* p = vt + (size_t)row * 2048 + lane * 32;
  float s = 0.f;
#pragma unroll
  for (int j = 0; j < 32; j += 8) {
    us8v v = *(const us8v*)(p + j);
#pragma unroll
    for (int e = 0; e < 8; e++) s += bf2f(v[e]);
  }
#pragma unroll
  for (int m = 1; m < 64; m <<= 1) s += __shfl_xor(s, m);
  if (lane == 0) vmean[row] = s * (1.0f / 2048.0f);
}

// ------------------------------------------------------------ flash attention
// Swapped QK^T: S^T = mfma(K_frag, Q_frag) => lane holds 16 scores for ONE
// q-row (q = c0), keys 16t+4g+r.  Softmax is lane-local + 2 shfl_xor (cross-g).
// Key-padding via __ballot bitmask; causal via 64-bit threshold mask; masked
// scores = -1e30 so exp underflows to exact 0.  P packed with v_cvt_pk_bf16_f32
// and written as 4x ds_write_b64 (XOR-granule swizzle, same as PV read).
// wg = (31-qt)*32 + bh: heavy q-tiles first; wg%8 == bh%8 keeps XCD locality.
__global__ __launch_bounds__(256) void k_attn(const unsigned short* __restrict__ qklin,
                                              const unsigned short* __restrict__ vt,
                                              const int* __restrict__ kpm,
                                              const float* __restrict__ vmean,
                                              unsigned short* __restrict__ ctx) {
  __shared__ unsigned short lds_k[2][64 * 64];
  __shared__ unsigned short lds_v[64 * 64];
  __shared__ unsigned short p_lds[4][16 * 64];
  int wg = blockIdx.x;
  int qt = 31 - (wg >> 5), bh = wg & 31;
  int b = bh >> 4, h = bh & 15;
  int tid = threadIdx.x, lane = tid & 63, w = tid >> 6;
  int g = lane >> 4, c0 = lane & 15;
  int q0 = qt * 64 + w * 16;
  unsigned short* pl = p_lds[w];
  int rrel = lane >> 3, gran = lane & 7;

  const unsigned short* ksrc0 = qklin + (size_t)(b * NS) * 2048 + 1024 + h * 64;
  const unsigned short* vsrc0 = vt + (size_t)(bh * 64) * 2048;

  const unsigned short* qbase = qklin + (size_t)(b * NS + q0 + c0) * 2048 + h * 64 + 8 * g;
  s8v qf0 = *(const s8v*)(qbase);
  s8v qf1 = *(const s8v*)(qbase + 32);

  f4v cacc[4];
#pragma unroll
  for (int d = 0; d < 4; d++) cacc[d] = (f4v){0.f, 0.f, 0.f, 0.f};
  float m_s = -1e30f, l_s = 0.f;       // per-lane running max/denom for q = q0+c0
  int qrow = q0 + c0;

  // prologue: stage K tile 0
#pragma unroll
  for (int i = 0; i < 2; i++) {
    int r = 16 * w + 8 * i + rrel;
    gload16(ksrc0 + (size_t)r * 2048 + 8 * (gran ^ rrel),
            (void*)(lds_k[0] + (16 * w + 8 * i) * 64));
  }
  __syncthreads();

  int nkt = qt + 1;
  for (int it = 0; it < nkt; ++it) {
    int kb = it * 64;
    int cur = it & 1;
    // ---- stage V(it) (consumed in PV this iter, after the barrier)
#pragma unroll
    for (int i = 0; i < 2; i++) {
      int r = 16 * w + 8 * i + rrel;
      gload16(vsrc0 + (size_t)r * 2048 + kb + 8 * (gran ^ rrel),
              (void*)(lds_v + (16 * w + 8 * i) * 64));
    }
    // ---- stage K(it+1) into the other buffer
    if (it < qt) {
#pragma unroll
      for (int i = 0; i < 2; i++) {
        int r = 16 * w + 8 * i + rrel;
        gload16(ksrc0 + (size_t)(kb + 64 + r) * 2048 + 8 * (gran ^ rrel),
                (void*)(lds_k[cur ^ 1] + (16 * w + 8 * i) * 64));
      }
    }
    // ---- key-padding mask (1 coalesced load + ballot)
    int kp = kpm[b * NS + kb + lane];
    uint64_t padmask = __ballot(kp != 0);
    // ---- scores: S^T tiles, lane holds q=c0, keys 16t+4g+r
    f4v sacc[4];
#pragma unroll
    for (int t = 0; t < 4; t++) {
      int row = 16 * t + c0;
      s8v kf0 = *(const s8v*)(lds_k[cur] + row * 64 + 8 * (g ^ (c0 & 7)));
      s8v kf1 = *(const s8v*)(lds_k[cur] + row * 64 + 8 * ((4 + g) ^ (c0 & 7)));
      f4v z = (f4v){0.f, 0.f, 0.f, 0.f};
      z = __builtin_amdgcn_mfma_f32_16x16x32_bf16(kf0, qf0, z, 0, 0, 0);
      z = __builtin_amdgcn_mfma_f32_16x16x32_bf16(kf1, qf1, z, 0, 0, 0);
      sacc[t] = z;
    }
    // ---- validity mask: causal threshold + padding
    int thr = qrow - kb;  // >= 0 always (kb <= qt*64 <= q0+c0)
    uint64_t cmask = (thr >= 63) ? ~0ull : ((2ull << thr) - 1ull);
    uint64_t valid = cmask & ~padmask;
    float p[4][4];
    float mx = -1e30f;
#pragma unroll
    for (int t = 0; t < 4; t++) {
      uint32_t nib = (uint32_t)(valid >> (16 * t + 4 * g)) & 0xFu;
#pragma unroll
      for (int r = 0; r < 4; r++) {
        float s = sacc[t][r];
        s = ((nib >> r) & 1u) ? s : -1e30f;
        p[t][r] = s;
      }
      mx = fmaxf(mx, fmaxf(fmaxf(p[t][0], p[t][1]), fmaxf(p[t][2], p[t][3])));
    }
    // cross-g reduce (lanes 16g+c0 share q-row c0)
    mx = fmaxf(mx, __shfl_xor(mx, 16));
    mx = fmaxf(mx, __shfl_xor(mx, 32));
    float mnew = fmaxf(m_s, mx);
    float a = __expf(m_s - mnew);
    float rs = 0.f;
#pragma unroll
    for (int t = 0; t < 4; t++)
#pragma unroll
      for (int r = 0; r < 4; r++) {
        float e = __expf(p[t][r] - mnew);  // masked: exp(-1e30 - m) == 0
        p[t][r] = e;
        rs += e;
      }
    rs += __shfl_xor(rs, 16);
    rs += __shfl_xor(rs, 32);
    rs = (mnew > -1e29f) ? rs : 0.f;     // row still fully masked -> l stays 0
    l_s = l_s * a + rs;
    m_s = mnew;
    // ---- redistribute rescale factor to cacc rows (q = 4g+r at this lane)
    {
      int ybase = 20 * g;  // lane 16g + (4g+r) holds a for q-row 4g+r
#pragma unroll
      for (int r = 0; r < 4; r++) {
        float ar = __shfl(a, ybase + r);
#pragma unroll
        for (int d = 0; d < 4; d++) cacc[d][r] *= ar;
      }
    }
    // ---- pack P -> LDS: row q=c0, cols 16t+4g+{0..3} = one b64 per t
#pragma unroll
    for (int t = 0; t < 4; t++) {
      u2v pk;
      pk[0] = cvtpk(p[t][0], p[t][1]);
      pk[1] = cvtpk(p[t][2], p[t][3]);
      int gr = (2 * t + (g >> 1)) ^ (c0 & 7);
      *(u2v*)((char*)pl + c0 * 128 + gr * 16 + 8 * (g & 1)) = pk;
    }
    // publishes: V(it)+K(it+1) staging (vmcnt drain) and P writes (lgkm)
    __syncthreads();
    // ---- PV from lds_v (unchanged layout: pf row q=c0, k-cols 8(g+4c))
#pragma unroll
    for (int c = 0; c < 2; c++) {
      int off = c0 * 128 + 16 * g + 64 * c;
      off ^= (c0 & 7) << 4;
      s8v pf = *(const s8v*)((const char*)pl + off);
#pragma unroll
      for (int d = 0; d < 4; d++) {
        int row = 16 * d + c0;
        s8v vf = *(const s8v*)(lds_v + row * 64 + 8 * ((4 * c + g) ^ (c0 & 7)));
        cacc[d] = __builtin_amdgcn_mfma_f32_16x16x32_bf16(pf, vf, cacc[d], 0, 0, 0);
      }
    }
    // all waves done reading lds_v / lds_k[cur] before next-iter staging
    __syncthreads();
  }
  // ---- epilogue: redistribute l to cacc rows, divide (or vmean fallback)
  float lq[4];
  {
    int ybase = 20 * g;
#pragma unroll
    for (int r = 0; r < 4; r++) lq[r] = __shfl(l_s, ybase + r);
  }
#pragma unroll
  for (int d = 0; d < 4; d++)
#pragma unroll
    for (int r = 0; r < 4; r++) {
      int q = q0 + 4 * g + r;
      float l = lq[r];
      float v = (l > 0.f) ? cacc[d][r] / l : vmean[bh * 64 + 16 * d + c0];
      ctx[(size_t)(b * NS + q) * ND + h * 64 + 16 * d + c0] = f2bf(v);
    }
}

// ----------------------------------------------------------------------------
extern "C" void kernel_launch(void* const* d_in, const int* in_sizes, int n_in,
                              void* d_out, int out_size, void* d_ws, size_t ws_size,
                              hipStream_t stream) {
  const float* x  = (const float*)d_in[0];
  const int* kpm  = (const int*)d_in[2];
  const float* Wq = (const float*)d_in[3];
  const float* Wk = (const float*)d_in[4];
  const float* Wv = (const float*)d_in[5];
  const float* Wo = (const float*)d_in[6];
  const float* bo = (const float*)d_in[7];

  char* ws = (char*)d_ws;
  unsigned short* xbf   = (unsigned short*)(ws);
  unsigned short* wtqkv = (unsigned short*)(ws + 8u * 1024 * 1024);
  unsigned short* wto   = (unsigned short*)(ws + 14u * 1024 * 1024);
  unsigned short* vt    = (unsigned short*)(ws + 16u * 1024 * 1024);
  float* vmean          = (float*)(ws + 24u * 1024 * 1024);
  unsigned short* ctx   = xbf;
  unsigned short* qklin = (unsigned short*)d_out;

  k_convert_x<<<4096, 256, 0, stream>>>(x, xbf);
  k_transpose_w<<<1024, 256, 0, stream>>>(Wq, Wk, Wv, Wo, wtqkv, wto);
  dim3 g0(24, 32);
  k_gemm<0><<<g0, 256, 0, stream>>>(xbf, wtqkv, qklin, vt, nullptr, nullptr);
  k_vmean<<<512, 256, 0, stream>>>(vt, vmean);
  k_attn<<<1024, 256, 0, stream>>>(qklin, vt, kpm, vmean, ctx);
  dim3 g1(8, 32);
  k_gemm<1><<<g1, 256, 0, stream>>>(ctx, wto, nullptr, nullptr, bo, (float*)d_out);
}

// Round 6
// 144.527 us; speedup vs baseline: 2.3505x; 1.0168x over previous
//
#include <hip/hip_runtime.h>
#include <stdint.h>

#define NB 2
#define NS 2048
#define ND 1024
#define NH 16
#define NDK 64

typedef __attribute__((ext_vector_type(8))) short s8v;
typedef __attribute__((ext_vector_type(4))) float f4v;
typedef __attribute__((ext_vector_type(4))) unsigned short us4v;
typedef __attribute__((ext_vector_type(8))) unsigned short us8v;
typedef __attribute__((ext_vector_type(2))) uint32_t u2v;

__device__ __forceinline__ unsigned short f2bf(float f) {
  uint32_t u = __builtin_bit_cast(uint32_t, f);
  u = (u + 0x7fffu + ((u >> 16) & 1u)) >> 16;
  return (unsigned short)u;
}
__device__ __forceinline__ float bf2f(unsigned short h) {
  uint32_t u = ((uint32_t)h) << 16;
  return __builtin_bit_cast(float, u);
}
// packed f32x2 -> bf16x2 (lo -> bits[15:0]), RNE
__device__ __forceinline__ uint32_t cvtpk(float lo, float hi) {
  uint32_t r;
  asm("v_cvt_pk_bf16_f32 %0, %1, %2" : "=v"(r) : "v"(lo), "v"(hi));
  return r;
}

__device__ __forceinline__ void gload16(const void* g, void* l) {
  __builtin_amdgcn_global_load_lds(
      (const __attribute__((address_space(1))) void*)g,
      (__attribute__((address_space(3))) void*)l, 16, 0, 0);
}

// ---------------------------------------------------------------- convert x
__global__ void k_convert_x(const float* __restrict__ x, unsigned short* __restrict__ xbf) {
  int i = (blockIdx.x * 256 + threadIdx.x) * 4;
  float4 v = *(const float4*)(x + i);
  us4v o;
  o[0] = f2bf(v.x); o[1] = f2bf(v.y); o[2] = f2bf(v.z); o[3] = f2bf(v.w);
  *(us4v*)(xbf + i) = o;
}

// ------------------------------------------------- transpose+convert weights
__global__ void k_transpose_w(const float* __restrict__ Wq, const float* __restrict__ Wk,
                              const float* __restrict__ Wv, const float* __restrict__ Wo,
                              unsigned short* __restrict__ wt_qkv, unsigned short* __restrict__ wt_o) {
  __shared__ float tls[64][65];
  int bid = blockIdx.x;
  int mat = bid >> 8;
  int tile = bid & 255;
  int tk = tile >> 4, tn = tile & 15;
  const float* W = (mat == 0) ? Wq : (mat == 1) ? Wk : (mat == 2) ? Wv : Wo;
  int t = threadIdx.x;
  int lr = t >> 2;
  int lc0 = (t & 3) * 16;
  const float* src = W + (size_t)(tk * 64 + lr) * 1024 + tn * 64 + lc0;
#pragma unroll
  for (int j = 0; j < 16; j += 4) {
    float4 v = *(const float4*)(src + j);
    tls[lr][lc0 + j + 0] = v.x; tls[lr][lc0 + j + 1] = v.y;
    tls[lr][lc0 + j + 2] = v.z; tls[lr][lc0 + j + 3] = v.w;
  }
  __syncthreads();
  float scale = (mat == 0) ? 0.125f : 1.0f;
  int nr = t >> 2, kc0 = (t & 3) * 16;
  unsigned short* dst = ((mat < 3) ? (wt_qkv + (size_t)(mat * 1024 + tn * 64 + nr) * 1024)
                                   : (wt_o + (size_t)(tn * 64 + nr) * 1024)) + tk * 64 + kc0;
  us8v o0, o1;
#pragma unroll
  for (int j = 0; j < 8; j++) o0[j] = f2bf(tls[kc0 + j][nr] * scale);
#pragma unroll
  for (int j = 0; j < 8; j++) o1[j] = f2bf(tls[kc0 + 8 + j][nr] * scale);
  *(us8v*)(dst) = o0;
  *(us8v*)(dst + 8) = o1;
}

// ----------------------------------------------------------------- bf16 GEMM
// 2-phase double-buffered pipeline (T3-minimum): STAGE(kt+1) issued BEFORE
// compute(kt); single __syncthreads per iter (its vmcnt(0) drain lands after
// the compute phase, hiding staging latency).  1-D grid, bijective XCD
// swizzle: each XCD owns contiguous M-rows (A panel in its L2, B from L3).
template <int MODE>
__global__ __launch_bounds__(256) void k_gemm(const unsigned short* __restrict__ A,
                                              const unsigned short* __restrict__ Bt,
                                              unsigned short* __restrict__ qklin,
                                              unsigned short* __restrict__ vt,
                                              const float* __restrict__ bias,
                                              float* __restrict__ out, int ntx) {
  __shared__ unsigned short lds_a[2][128 * 64];
  __shared__ unsigned short lds_b[2][128 * 64];
  const int K = 1024;
  int bid = blockIdx.x;
  int qc = gridDim.x >> 3;  // grid %8 == 0
  int swz = (bid & 7) * qc + (bid >> 3);
  int m0 = (swz / ntx) * 128, n0 = (swz % ntx) * 128;
  int tid = threadIdx.x, lane = tid & 63, w = tid >> 6;
  int wm = w >> 1, wn = w & 1;
  int g = lane >> 4, c0 = lane & 15;
  int rrel = lane >> 3;
  int gran = lane & 7;
  f4v acc[4][4];
#pragma unroll
  for (int mi = 0; mi < 4; mi++)
#pragma unroll
    for (int ni = 0; ni < 4; ni++) acc[mi][ni] = (f4v){0.f, 0.f, 0.f, 0.f};

  // prologue: stage kt=0 into buf 0
#pragma unroll
  for (int i = 0; i < 4; i++) {
    int r = 32 * w + 8 * i + rrel;
    gload16(A + (size_t)(m0 + r) * K + 8 * (gran ^ rrel),
            (void*)(lds_a[0] + (32 * w + 8 * i) * 64));
    gload16(Bt + (size_t)(n0 + r) * K + 8 * (gran ^ rrel),
            (void*)(lds_b[0] + (32 * w + 8 * i) * 64));
  }
  __syncthreads();

  for (int kt = 0; kt < K / 64; ++kt) {
    int cur = kt & 1;
    // ---- stage kt+1 into the other buffer (awaited at end-of-iter barrier)
    if (kt < K / 64 - 1) {
#pragma unroll
      for (int i = 0; i < 4; i++) {
        int r = 32 * w + 8 * i + rrel;
        gload16(A + (size_t)(m0 + r) * K + (kt + 1) * 64 + 8 * (gran ^ rrel),
                (void*)(lds_a[cur ^ 1] + (32 * w + 8 * i) * 64));
        gload16(Bt + (size_t)(n0 + r) * K + (kt + 1) * 64 + 8 * (gran ^ rrel),
                (void*)(lds_b[cur ^ 1] + (32 * w + 8 * i) * 64));
      }
    }
    // ---- compute from buf[cur]
#pragma unroll
    for (int c = 0; c < 2; c++) {
      s8v af[4], bfr[4];
#pragma unroll
      for (int mi = 0; mi < 4; mi++) {
        int row = 64 * wm + 16 * mi + c0;
        af[mi] = *(const s8v*)(lds_a[cur] + row * 64 + 8 * ((g + 4 * c) ^ (c0 & 7)));
      }
#pragma unroll
      for (int ni = 0; ni < 4; ni++) {
        int row = 64 * wn + 16 * ni + c0;
        bfr[ni] = *(const s8v*)(lds_b[cur] + row * 64 + 8 * ((g + 4 * c) ^ (c0 & 7)));
      }
#pragma unroll
      for (int mi = 0; mi < 4; mi++)
#pragma unroll
        for (int ni = 0; ni < 4; ni++)
          acc[mi][ni] = __builtin_amdgcn_mfma_f32_16x16x32_bf16(af[mi], bfr[ni], acc[mi][ni], 0, 0, 0);
    }
    // single barrier per iter: drains staging vmcnt + orders LDS reuse
    __syncthreads();
  }

#pragma unroll
  for (int mi = 0; mi < 4; mi++)
#pragma unroll
    for (int ni = 0; ni < 4; ni++)
#pragma unroll
      for (int r = 0; r < 4; r++) {
        int m = m0 + 64 * wm + 16 * mi + 4 * g + r;
        int n = n0 + 64 * wn + 16 * ni + c0;
        float v = acc[mi][ni][r];
        if (MODE == 0) {
          unsigned short hv = f2bf(v);
          if (n < 2048) {
            qklin[(size_t)m * 2048 + n] = hv;
          } else {
            int b = m >> 11, s = m & 2047;
            int hh = (n - 2048) >> 6, dk = n & 63;
            vt[(size_t)((b * 16 + hh) * 64 + dk) * 2048 + s] = hv;
          }
        } else {
          out[(size_t)m * 1024 + n] = v + bias[n];
        }
      }
}

// ----------------------------------------------------------------- V row mean
__global__ void k_vmean(const unsigned short* __restrict__ vt, float* __restrict__ vmean) {
  int row = blockIdx.x * 4 + (threadIdx.x >> 6);
  int lane = threadIdx.x & 63;
  const unsigned short* p = vt + (size_t)row * 2048 + lane * 32;
  float s = 0.f;
#pragma unroll
  for (int j = 0; j < 32; j += 8) {
    us8v v = *(const us8v*)(p + j);
#pragma unroll
    for (int e = 0; e < 8; e++) s += bf2f(v[e]);
  }
#pragma unroll
  for (int m = 1; m < 64; m <<= 1) s += __shfl_xor(s, m);
  if (lane == 0) vmean[row] = s * (1.0f / 2048.0f);
}

// ------------------------------------------------------------ flash attention
// Swapped QK^T: S^T = mfma(K_frag, Q_frag) => lane holds 16 scores for ONE
// q-row (q = c0), keys 16t+4g+r.  Softmax is lane-local + 2 shfl_xor (cross-g).
__global__ __launch_bounds__(256) void k_attn(const unsigned short* __restrict__ qklin,
                                              const unsigned short* __restrict__ vt,
                                              const int* __restrict__ kpm,
                                              const float* __restrict__ vmean,
                                              unsigned short* __restrict__ ctx) {
  __shared__ unsigned short lds_k[2][64 * 64];
  __shared__ unsigned short lds_v[64 * 64];
  __shared__ unsigned short p_lds[4][16 * 64];
  int wg = blockIdx.x;
  int qt = 31 - (wg >> 5), bh = wg & 31;
  int b = bh >> 4, h = bh & 15;
  int tid = threadIdx.x, lane = tid & 63, w = tid >> 6;
  int g = lane >> 4, c0 = lane & 15;
  int q0 = qt * 64 + w * 16;
  unsigned short* pl = p_lds[w];
  int rrel = lane >> 3, gran = lane & 7;

  const unsigned short* ksrc0 = qklin + (size_t)(b * NS) * 2048 + 1024 + h * 64;
  const unsigned short* vsrc0 = vt + (size_t)(bh * 64) * 2048;

  const unsigned short* qbase = qklin + (size_t)(b * NS + q0 + c0) * 2048 + h * 64 + 8 * g;
  s8v qf0 = *(const s8v*)(qbase);
  s8v qf1 = *(const s8v*)(qbase + 32);

  f4v cacc[4];
#pragma unroll
  for (int d = 0; d < 4; d++) cacc[d] = (f4v){0.f, 0.f, 0.f, 0.f};
  float m_s = -1e30f, l_s = 0.f;
  int qrow = q0 + c0;

  // prologue: stage K tile 0
#pragma unroll
  for (int i = 0; i < 2; i++) {
    int r = 16 * w + 8 * i + rrel;
    gload16(ksrc0 + (size_t)r * 2048 + 8 * (gran ^ rrel),
            (void*)(lds_k[0] + (16 * w + 8 * i) * 64));
  }
  __syncthreads();

  int nkt = qt + 1;
  for (int it = 0; it < nkt; ++it) {
    int kb = it * 64;
    int cur = it & 1;
    // ---- stage V(it) (consumed in PV this iter, after the barrier)
#pragma unroll
    for (int i = 0; i < 2; i++) {
      int r = 16 * w + 8 * i + rrel;
      gload16(vsrc0 + (size_t)r * 2048 + kb + 8 * (gran ^ rrel),
              (void*)(lds_v + (16 * w + 8 * i) * 64));
    }
    // ---- stage K(it+1) into the other buffer
    if (it < qt) {
#pragma unroll
      for (int i = 0; i < 2; i++) {
        int r = 16 * w + 8 * i + rrel;
        gload16(ksrc0 + (size_t)(kb + 64 + r) * 2048 + 8 * (gran ^ rrel),
                (void*)(lds_k[cur ^ 1] + (16 * w + 8 * i) * 64));
      }
    }
    // ---- key-padding mask (1 coalesced load + ballot)
    int kp = kpm[b * NS + kb + lane];
    uint64_t padmask = __ballot(kp != 0);
    // ---- scores: S^T tiles, lane holds q=c0, keys 16t+4g+r
    f4v sacc[4];
#pragma unroll
    for (int t = 0; t < 4; t++) {
      int row = 16 * t + c0;
      s8v kf0 = *(const s8v*)(lds_k[cur] + row * 64 + 8 * (g ^ (c0 & 7)));
      s8v kf1 = *(const s8v*)(lds_k[cur] + row * 64 + 8 * ((4 + g) ^ (c0 & 7)));
      f4v z = (f4v){0.f, 0.f, 0.f, 0.f};
      z = __builtin_amdgcn_mfma_f32_16x16x32_bf16(kf0, qf0, z, 0, 0, 0);
      z = __builtin_amdgcn_mfma_f32_16x16x32_bf16(kf1, qf1, z, 0, 0, 0);
      sacc[t] = z;
    }
    // ---- validity mask: causal threshold + padding
    int thr = qrow - kb;
    uint64_t cmask = (thr >= 63) ? ~0ull : ((2ull << thr) - 1ull);
    uint64_t valid = cmask & ~padmask;
    float p[4][4];
    float mx = -1e30f;
#pragma unroll
    for (int t = 0; t < 4; t++) {
      uint32_t nib = (uint32_t)(valid >> (16 * t + 4 * g)) & 0xFu;
#pragma unroll
      for (int r = 0; r < 4; r++) {
        float s = sacc[t][r];
        s = ((nib >> r) & 1u) ? s : -1e30f;
        p[t][r] = s;
      }
      mx = fmaxf(mx, fmaxf(fmaxf(p[t][0], p[t][1]), fmaxf(p[t][2], p[t][3])));
    }
    mx = fmaxf(mx, __shfl_xor(mx, 16));
    mx = fmaxf(mx, __shfl_xor(mx, 32));
    float mnew = fmaxf(m_s, mx);
    float a = __expf(m_s - mnew);
    float rs = 0.f;
#pragma unroll
    for (int t = 0; t < 4; t++)
#pragma unroll
      for (int r = 0; r < 4; r++) {
        float e = __expf(p[t][r] - mnew);
        p[t][r] = e;
        rs += e;
      }
    rs += __shfl_xor(rs, 16);
    rs += __shfl_xor(rs, 32);
    rs = (mnew > -1e29f) ? rs : 0.f;
    l_s = l_s * a + rs;
    m_s = mnew;
    // ---- redistribute rescale factor to cacc rows (q = 4g+r at this lane)
    {
      int ybase = 20 * g;
#pragma unroll
      for (int r = 0; r < 4; r++) {
        float ar = __shfl(a, ybase + r);
#pragma unroll
        for (int d = 0; d < 4; d++) cacc[d][r] *= ar;
      }
    }
    // ---- pack P -> LDS: row q=c0, cols 16t+4g+{0..3} = one b64 per t
#pragma unroll
    for (int t = 0; t < 4; t++) {
      u2v pk;
      pk[0] = cvtpk(p[t][0], p[t][1]);
      pk[1] = cvtpk(p[t][2], p[t][3]);
      int gr = (2 * t + (g >> 1)) ^ (c0 & 7);
      *(u2v*)((char*)pl + c0 * 128 + gr * 16 + 8 * (g & 1)) = pk;
    }
    __syncthreads();
    // ---- PV from lds_v
#pragma unroll
    for (int c = 0; c < 2; c++) {
      int off = c0 * 128 + 16 * g + 64 * c;
      off ^= (c0 & 7) << 4;
      s8v pf = *(const s8v*)((const char*)pl + off);
#pragma unroll
      for (int d = 0; d < 4; d++) {
        int row = 16 * d + c0;
        s8v vf = *(const s8v*)(lds_v + row * 64 + 8 * ((4 * c + g) ^ (c0 & 7)));
        cacc[d] = __builtin_amdgcn_mfma_f32_16x16x32_bf16(pf, vf, cacc[d], 0, 0, 0);
      }
    }
    __syncthreads();
  }
  // ---- epilogue
  float lq[4];
  {
    int ybase = 20 * g;
#pragma unroll
    for (int r = 0; r < 4; r++) lq[r] = __shfl(l_s, ybase + r);
  }
#pragma unroll
  for (int d = 0; d < 4; d++)
#pragma unroll
    for (int r = 0; r < 4; r++) {
      int q = q0 + 4 * g + r;
      float l = lq[r];
      float v = (l > 0.f) ? cacc[d][r] / l : vmean[bh * 64 + 16 * d + c0];
      ctx[(size_t)(b * NS + q) * ND + h * 64 + 16 * d + c0] = f2bf(v);
    }
}

// ----------------------------------------------------------------------------
extern "C" void kernel_launch(void* const* d_in, const int* in_sizes, int n_in,
                              void* d_out, int out_size, void* d_ws, size_t ws_size,
                              hipStream_t stream) {
  const float* x  = (const float*)d_in[0];
  const int* kpm  = (const int*)d_in[2];
  const float* Wq = (const float*)d_in[3];
  const float* Wk = (const float*)d_in[4];
  const float* Wv = (const float*)d_in[5];
  const float* Wo = (const float*)d_in[6];
  const float* bo = (const float*)d_in[7];

  char* ws = (char*)d_ws;
  unsigned short* xbf   = (unsigned short*)(ws);
  unsigned short* wtqkv = (unsigned short*)(ws + 8u * 1024 * 1024);
  unsigned short* wto   = (unsigned short*)(ws + 14u * 1024 * 1024);
  unsigned short* vt    = (unsigned short*)(ws + 16u * 1024 * 1024);
  float* vmean          = (float*)(ws + 24u * 1024 * 1024);
  unsigned short* ctx   = xbf;
  unsigned short* qklin = (unsigned short*)d_out;

  k_convert_x<<<4096, 256, 0, stream>>>(x, xbf);
  k_transpose_w<<<1024, 256, 0, stream>>>(Wq, Wk, Wv, Wo, wtqkv, wto);
  k_gemm<0><<<768, 256, 0, stream>>>(xbf, wtqkv, qklin, vt, nullptr, nullptr, 24);
  k_vmean<<<512, 256, 0, stream>>>(vt, vmean);
  k_attn<<<1024, 256, 0, stream>>>(qklin, vt, kpm, vmean, ctx);
  k_gemm<1><<<256, 256, 0, stream>>>(ctx, wto, nullptr, nullptr, bo, (float*)d_out, 8);
}